// Round 7
// baseline (201.070 us; speedup 1.0000x reference)
//
#include <hip/hip_runtime.h>

#define N_NODES 50000
#define N_EDGES 400000
#define DIM 160
#define NB 64
#define CUTOFF 5.0f
#define LN_EPS 1e-5f
#define PI_F 3.14159265358979323846f

// Padded CSR: stride-64 slot list per destination node.
// max in-degree ~ Poisson(8) over 50k nodes ~ 28; P(>=64) ~ 1e-40.
#define SLOT_STRIDE 64

// deg padded to one counter per 16B (4/64B-line): keeps total ws <= 16 MiB.
#define DEG_STRIDE 4

// Workspace (ints), total 3,600,272 ints = 13.73 MiB (< 16 MiB cap):
//   [0..15]     ew accumulator (float) + pad
//   degp[N*4]   16B-padded degree counters (0.8 MB)
//   pkt[64]     (float4 per RBF bucket: {center, 1/width, proj_w, 0})
//   pos4[N]     (float4 per node)
//   esrc[N*64]  padded CSR slots (12.8 MB)
#define WS_DEG   16
#define WS_PKT   (WS_DEG + N_NODES * DEG_STRIDE)   // 200016 -> 16B aligned
#define WS_POS4  (WS_PKT + 4 * NB)                 // 200272 -> 16B aligned
#define WS_ESRC  (WS_POS4 + 4 * N_NODES)           // 400272 -> 16B aligned

// ---------------------------------------------------------------------------
// K0: prep. Zeroes ew + padded deg (one int4 per node), packs pos into
// float4 rows, packs RBF table into one float4 per bucket.
// ---------------------------------------------------------------------------
__global__ __launch_bounds__(256) void prep(
    const float* __restrict__ pos, const float* __restrict__ centers,
    const float* __restrict__ widths, const float* __restrict__ proj_w,
    int* __restrict__ degp, float4* __restrict__ pkt,
    float4* __restrict__ pos4, float* __restrict__ ew_accum)
{
    const int i = blockIdx.x * blockDim.x + threadIdx.x;
    if (i < 16) ((int*)ew_accum)[i] = 0;
    if (i < NB)
        pkt[i] = make_float4(centers[i], 1.0f / widths[i], proj_w[i], 0.0f);
    if (i < N_NODES) {
        ((int4*)(degp))[i] = make_int4(0, 0, 0, 0);   // one 16B line per node
        pos4[i] = make_float4(pos[3 * i], pos[3 * i + 1], pos[3 * i + 2], 0.0f);
    }
}

// ---------------------------------------------------------------------------
// K1: 4 edges per thread. Fused: edge_w sigmoid sum + degree count + padded-
// CSR slot fill. The 4 atomic-with-return chains and 8 pos4 loads are all
// independent (memory-level parallelism); RBF evals share each pkt[b] load.
// ---------------------------------------------------------------------------
#define EPT 4

__global__ __launch_bounds__(256) void hist_ew_fill(
    const int* __restrict__ ei, const float4* __restrict__ pos4,
    const float4* __restrict__ pkt, const float* __restrict__ proj_b,
    int* __restrict__ degp, int* __restrict__ esrc, float* __restrict__ ew_accum)
{
    const float bias = proj_b[0];
    const int base = blockIdx.x * (256 * EPT) + threadIdx.x;

    int  s[EPT], d[EPT], slot[EPT];
    bool v[EPT];
    #pragma unroll
    for (int k = 0; k < EPT; ++k) {
        const int e = base + 256 * k;
        v[k] = (e < N_EDGES);
        s[k] = v[k] ? ei[e] : 0;
        d[k] = v[k] ? ei[N_EDGES + e] : 0;
    }

    #pragma unroll
    for (int k = 0; k < EPT; ++k)
        slot[k] = v[k] ? atomicAdd(&degp[(long)d[k] * DEG_STRIDE], 1) : 0;

    float4 ps[EPT], pd[EPT];
    #pragma unroll
    for (int k = 0; k < EPT; ++k) { ps[k] = pos4[s[k]]; pd[k] = pos4[d[k]]; }

    #pragma unroll
    for (int k = 0; k < EPT; ++k)
        if (v[k] && slot[k] < SLOT_STRIDE)
            esrc[((long)d[k] << 6) + slot[k]] = s[k];

    float dist[EPT];
    #pragma unroll
    for (int k = 0; k < EPT; ++k) {
        const float dx = ps[k].x - pd[k].x;
        const float dy = ps[k].y - pd[k].y;
        const float dz = ps[k].z - pd[k].z;
        dist[k] = sqrtf(dx * dx + dy * dy + dz * dz);
    }

    float z[EPT] = {0.f, 0.f, 0.f, 0.f};
    #pragma unroll 4
    for (int b = 0; b < NB; ++b) {
        const float4 t4 = pkt[b];               // broadcast, L1-hot
        #pragma unroll
        for (int k = 0; k < EPT; ++k) {
            const float t = (dist[k] - t4.x) * t4.y;
            z[k] = fmaf(__expf(-0.5f * t * t), t4.z, z[k]);
        }
    }

    float sig = 0.0f;
    #pragma unroll
    for (int k = 0; k < EPT; ++k) {
        if (v[k]) {
            const float cut = (dist[k] <= CUTOFF)
                            ? 0.5f * (__cosf(PI_F * dist[k] * (1.0f / CUTOFF)) + 1.0f)
                            : 0.0f;
            sig += 1.0f / (1.0f + __expf(-(z[k] * cut + bias)));
        }
    }

    #pragma unroll
    for (int off = 32; off > 0; off >>= 1) sig += __shfl_xor(sig, off);
    __shared__ float red[4];
    if ((threadIdx.x & 63) == 0) red[threadIdx.x >> 6] = sig;
    __syncthreads();
    if (threadIdx.x == 0)
        atomicAdd(ew_accum, red[0] + red[1] + red[2] + red[3]);
}

// ---------------------------------------------------------------------------
// K2: gather, thread-per-(node, float4-chunk). Block owns 32 nodes = 1280
// tasks = 5 x 256. ALL 64 lanes issue row loads (vs 40/64 before) and each
// lane has a 16-deep unrolled independent load stream (slots prefetched as
// 4x int4; P(deg>16) ~ 0.4% handled by scalar tail). Fix for round-6
// finding: gather was issue-slot starved (3.7 TB/s, 63% occ, 14% VALU).
// ---------------------------------------------------------------------------
#define GNODES 32   // nodes per block

__global__ __launch_bounds__(256) void gather_pass(
    const float* __restrict__ x, const int* __restrict__ degp,
    const int* __restrict__ esrc, float* __restrict__ agg)
{
    const int node0 = blockIdx.x * GNODES;
    #pragma unroll
    for (int it = 0; it < 5; ++it) {
        const int t2 = it * 256 + threadIdx.x;     // 0..1279
        const int nl = t2 / 40;                    // magic-mul
        const int c  = t2 - nl * 40;               // float4 chunk 0..39
        const int n  = node0 + nl;
        if (n >= N_NODES) continue;

        const int cnt = min(degp[(long)n * DEG_STRIDE], SLOT_STRIDE);
        const int4* sl4 = (const int4*)(esrc + ((long)n << 6));
        const int4 sa = sl4[0];
        const int4 sb = sl4[1];
        const int4 sc = sl4[2];
        const int4 sd = sl4[3];
        const int sj[16] = { sa.x, sa.y, sa.z, sa.w,  sb.x, sb.y, sb.z, sb.w,
                             sc.x, sc.y, sc.z, sc.w,  sd.x, sd.y, sd.z, sd.w };

        float4 acc = make_float4(0.f, 0.f, 0.f, 0.f);
        #pragma unroll
        for (int j = 0; j < 16; ++j) {
            if (j < cnt) {
                const float4 v = *(const float4*)(x + (long)sj[j] * DIM + 4 * c);
                acc.x += v.x; acc.y += v.y; acc.z += v.z; acc.w += v.w;
            }
        }
        for (int j = 16; j < cnt; ++j) {          // rare tail
            const int s = esrc[((long)n << 6) + j];
            const float4 v = *(const float4*)(x + (long)s * DIM + 4 * c);
            acc.x += v.x; acc.y += v.y; acc.z += v.z; acc.w += v.w;
        }
        *(float4*)(agg + (long)n * DIM + 4 * c) = acc;
    }
}

// ---------------------------------------------------------------------------
// K3: LDS-tiled node transform. Block owns 64 nodes; rows + W0 + W1 in LDS.
// Scalar channel: thread = (node-quad, output-quad); per k-quad loads
// 4x b128 aRow + 4x b128 W0-rows -> 8 LDS instrs per 64 FMA.
// Vector channel: thread = (node, c8). LDS = 62464 B -> 2 blocks/CU.
// ---------------------------------------------------------------------------
#define ROWP 164
#define TNODES 64

__global__ __launch_bounds__(256) void node_tiled(
    float* __restrict__ agg,
    const float* __restrict__ W0, const float* __restrict__ W1,
    const float* __restrict__ ln_gamma, const float* __restrict__ ln_beta,
    const float* __restrict__ ew_accum)
{
    __shared__ float sA[TNODES * ROWP];   // 64 x 164 floats
    __shared__ float sW0[64 * 64];
    __shared__ float sW1[32 * 32];

    const int t = threadIdx.x;
    const int node0 = blockIdx.x * TNODES;

    // ---- stage weights (coalesced, L2-hot) ----
    {
        const float4* w04 = (const float4*)W0;   // 1024 float4
        float4* s04 = (float4*)sW0;
        #pragma unroll
        for (int i = 0; i < 4; ++i) s04[t + 256 * i] = w04[t + 256 * i];
        ((float4*)sW1)[t] = ((const float4*)W1)[t];   // 256 float4
    }
    // ---- stage 64 rows (coalesced float4, guarded) ----
    {
        #pragma unroll
        for (int i = 0; i < 10; ++i) {
            const int idx = t + 256 * i;         // 0..2559
            const int r   = idx / 40;
            const int c4  = idx - r * 40;
            const int n   = node0 + r;
            float4 v = make_float4(0.f, 0.f, 0.f, 0.f);
            if (n < N_NODES) v = ((const float4*)(agg + (long)n * DIM))[c4];
            *(float4*)(&sA[r * ROWP + 4 * c4]) = v;
        }
    }
    __syncthreads();

    const float ew   = ew_accum[0] * (1.0f / 400000.0f);
    const float s_m0 = ew * 0.125f;                 // / sqrt(64)
    const float s_m1 = ew * 0.17677669529663687f;   // / sqrt(32)

    // ---------------- scalar channel (node-quad x output-quad) ----------------
    {
        const int q   = t >> 4;          // 0..15 node quad: nodes 4q..4q+3
        const int sub = t & 15;          // 0..15 output quad: outs 4sub..4sub+3
        const float* r0 = sA + (4 * q + 0) * ROWP;
        const float* r1 = sA + (4 * q + 1) * ROWP;
        const float* r2 = sA + (4 * q + 2) * ROWP;
        const float* r3 = sA + (4 * q + 3) * ROWP;

        float acc[4][4];
        #pragma unroll
        for (int n = 0; n < 4; ++n)
            #pragma unroll
            for (int j = 0; j < 4; ++j) acc[n][j] = 0.0f;

        #pragma unroll 4
        for (int k0 = 0; k0 < 64; k0 += 4) {
            const float4 a0 = *(const float4*)(r0 + k0);
            const float4 a1 = *(const float4*)(r1 + k0);
            const float4 a2 = *(const float4*)(r2 + k0);
            const float4 a3 = *(const float4*)(r3 + k0);
            const float4 w0 = *(const float4*)(sW0 + (k0 + 0) * 64 + 4 * sub);
            const float4 w1 = *(const float4*)(sW0 + (k0 + 1) * 64 + 4 * sub);
            const float4 w2 = *(const float4*)(sW0 + (k0 + 2) * 64 + 4 * sub);
            const float4 w3 = *(const float4*)(sW0 + (k0 + 3) * 64 + 4 * sub);
            #define FMA4(A, av, wv) \
                A[0] = fmaf(av, wv.x, A[0]); A[1] = fmaf(av, wv.y, A[1]); \
                A[2] = fmaf(av, wv.z, A[2]); A[3] = fmaf(av, wv.w, A[3]);
            FMA4(acc[0], a0.x, w0) FMA4(acc[0], a0.y, w1) FMA4(acc[0], a0.z, w2) FMA4(acc[0], a0.w, w3)
            FMA4(acc[1], a1.x, w0) FMA4(acc[1], a1.y, w1) FMA4(acc[1], a1.z, w2) FMA4(acc[1], a1.w, w3)
            FMA4(acc[2], a2.x, w0) FMA4(acc[2], a2.y, w1) FMA4(acc[2], a2.z, w2) FMA4(acc[2], a2.w, w3)
            FMA4(acc[3], a3.x, w0) FMA4(acc[3], a3.y, w1) FMA4(acc[3], a3.z, w2) FMA4(acc[3], a3.w, w3)
            #undef FMA4
        }

        float sum[4], ssq[4];
        #pragma unroll
        for (int n = 0; n < 4; ++n) {
            sum[n] = 0.0f; ssq[n] = 0.0f;
            #pragma unroll
            for (int j = 0; j < 4; ++j) {
                acc[n][j] *= s_m0;
                sum[n] += acc[n][j];
                ssq[n] = fmaf(acc[n][j], acc[n][j], ssq[n]);
            }
        }
        #pragma unroll
        for (int m = 1; m <= 8; m <<= 1) {
            #pragma unroll
            for (int n = 0; n < 4; ++n) {
                sum[n] += __shfl_xor(sum[n], m);
                ssq[n] += __shfl_xor(ssq[n], m);
            }
        }

        const float4 g = *(const float4*)(ln_gamma + 4 * sub);
        const float4 b = *(const float4*)(ln_beta  + 4 * sub);
        #pragma unroll
        for (int n = 0; n < 4; ++n) {
            const int node = node0 + 4 * q + n;
            if (node < N_NODES) {
                const float mu   = sum[n] * (1.0f / 64.0f);
                const float var  = ssq[n] * (1.0f / 64.0f) - mu * mu;
                const float rstd = rsqrtf(var + LN_EPS);
                const float t0 = (acc[n][0] - mu) * rstd * g.x + b.x;
                const float t1 = (acc[n][1] - mu) * rstd * g.y + b.y;
                const float t2 = (acc[n][2] - mu) * rstd * g.z + b.z;
                const float t3 = (acc[n][3] - mu) * rstd * g.w + b.w;
                float4 o;
                o.x = t0 / (1.0f + __expf(-t0));
                o.y = t1 / (1.0f + __expf(-t1));
                o.z = t2 / (1.0f + __expf(-t2));
                o.w = t3 / (1.0f + __expf(-t3));
                *(float4*)(agg + (long)node * DIM + 4 * sub) = o;
            }
        }
    }

    // ---------------- vector channel (unchanged mapping) ----------------
    {
        const int nl   = t >> 2;          // 0..63 node within tile
        const int sub  = t & 3;           // c8
        const int node = node0 + nl;
        const bool valid = node < N_NODES;
        float* grow = agg + (long)(valid ? node : 0) * DIM;
        const float* aRow = sA + nl * ROWP;

        float o[24];
        #pragma unroll
        for (int m = 0; m < 24; ++m) o[m] = 0.0f;

        const float* bRow = aRow + 64;
        #pragma unroll 2
        for (int tt = 0; tt < 8; ++tt) {            // cp = 4tt + r
            const float4 v0 = *(const float4*)(bRow + 12 * tt);
            const float4 v1 = *(const float4*)(bRow + 12 * tt + 4);
            const float4 v2 = *(const float4*)(bRow + 12 * tt + 8);
            const float a[12] = { v0.x, v0.y, v0.z, v0.w,
                                  v1.x, v1.y, v1.z, v1.w,
                                  v2.x, v2.y, v2.z, v2.w };
            #pragma unroll
            for (int r = 0; r < 4; ++r) {
                const int cp = 4 * tt + r;
                const float a0 = a[3 * r];
                const float a1 = a[3 * r + 1];
                const float a2 = a[3 * r + 2];
                const float4* w4 = (const float4*)(sW1 + cp * 32 + sub * 8);
                const float4 wA = w4[0];
                const float4 wB = w4[1];
                const float wc[8] = { wA.x, wA.y, wA.z, wA.w, wB.x, wB.y, wB.z, wB.w };
                #pragma unroll
                for (int cc = 0; cc < 8; ++cc) {
                    o[3 * cc]     = fmaf(wc[cc], a0, o[3 * cc]);
                    o[3 * cc + 1] = fmaf(wc[cc], a1, o[3 * cc + 1]);
                    o[3 * cc + 2] = fmaf(wc[cc], a2, o[3 * cc + 2]);
                }
            }
        }

        if (valid) {
            float4* ro4 = (float4*)(grow + 64 + 24 * sub);
            #pragma unroll
            for (int q2 = 0; q2 < 6; ++q2) {
                float4 ov;
                ov.x = o[4 * q2]     * s_m1;
                ov.y = o[4 * q2 + 1] * s_m1;
                ov.z = o[4 * q2 + 2] * s_m1;
                ov.w = o[4 * q2 + 3] * s_m1;
                ro4[q2] = ov;
            }
        }
    }
}

extern "C" void kernel_launch(void* const* d_in, const int* in_sizes, int n_in,
                              void* d_out, int out_size, void* d_ws, size_t ws_size,
                              hipStream_t stream) {
    const float* x       = (const float*)d_in[0];
    const float* pos     = (const float*)d_in[1];
    const int*   ei      = (const int*)d_in[2];
    const float* W0      = (const float*)d_in[4];
    const float* W1      = (const float*)d_in[5];
    const float* centers = (const float*)d_in[6];
    const float* widths  = (const float*)d_in[7];
    const float* proj_w  = (const float*)d_in[8];
    const float* proj_b  = (const float*)d_in[9];
    const float* gamma   = (const float*)d_in[10];
    const float* beta    = (const float*)d_in[11];

    float* out  = (float*)d_out;
    int*   wsi  = (int*)d_ws;
    float* ew   = (float*)d_ws;
    int*   degp = wsi + WS_DEG;
    float4* pkt  = (float4*)(wsi + WS_PKT);
    float4* pos4 = (float4*)(wsi + WS_POS4);
    int*   esrc = wsi + WS_ESRC;

    const int pb = (N_NODES + 255) / 256;
    prep<<<pb, 256, 0, stream>>>(pos, centers, widths, proj_w, degp, pkt, pos4, ew);

    const int eb = (N_EDGES + 256 * EPT - 1) / (256 * EPT);   // 391
    hist_ew_fill<<<eb, 256, 0, stream>>>(ei, pos4, pkt, proj_b, degp, esrc, ew);

    const int gb = (N_NODES + GNODES - 1) / GNODES;   // 1563
    gather_pass<<<gb, 256, 0, stream>>>(x, degp, esrc, out);

    const int tiles = (N_NODES + TNODES - 1) / TNODES;   // 782
    node_tiled<<<tiles, 256, 0, stream>>>(out, W0, W1, gamma, beta, ew);
}

// Round 8
// 200.946 us; speedup vs baseline: 1.0006x; 1.0006x over previous
//
#include <hip/hip_runtime.h>

#define N_NODES 50000
#define N_EDGES 400000
#define DIM 160
#define NB 64
#define CUTOFF 5.0f
#define LN_EPS 1e-5f
#define PI_F 3.14159265358979323846f

// Padded CSR: stride-64 slot list per destination node.
#define SLOT_STRIDE 64
// deg padded to one counter per 16B.
#define DEG_STRIDE 4

// Workspace (ints), total 3,600,272 ints = 13.73 MiB:
#define WS_DEG   16
#define WS_PKT   (WS_DEG + N_NODES * DEG_STRIDE)   // 200016
#define WS_POS4  (WS_PKT + 4 * NB)                 // 200272
#define WS_ESRC  (WS_POS4 + 4 * N_NODES)           // 400272

// ---------------------------------------------------------------------------
// K0: prep (unchanged).
// ---------------------------------------------------------------------------
__global__ __launch_bounds__(256) void prep(
    const float* __restrict__ pos, const float* __restrict__ centers,
    const float* __restrict__ widths, const float* __restrict__ proj_w,
    int* __restrict__ degp, float4* __restrict__ pkt,
    float4* __restrict__ pos4, float* __restrict__ ew_accum)
{
    const int i = blockIdx.x * blockDim.x + threadIdx.x;
    if (i < 16) ((int*)ew_accum)[i] = 0;
    if (i < NB)
        pkt[i] = make_float4(centers[i], 1.0f / widths[i], proj_w[i], 0.0f);
    if (i < N_NODES) {
        ((int4*)(degp))[i] = make_int4(0, 0, 0, 0);
        pos4[i] = make_float4(pos[3 * i], pos[3 * i + 1], pos[3 * i + 2], 0.0f);
    }
}

// ---------------------------------------------------------------------------
// K1: hist_ew_fill (unchanged from round 5/6).
// ---------------------------------------------------------------------------
#define EPT 4

__global__ __launch_bounds__(256) void hist_ew_fill(
    const int* __restrict__ ei, const float4* __restrict__ pos4,
    const float4* __restrict__ pkt, const float* __restrict__ proj_b,
    int* __restrict__ degp, int* __restrict__ esrc, float* __restrict__ ew_accum)
{
    const float bias = proj_b[0];
    const int base = blockIdx.x * (256 * EPT) + threadIdx.x;

    int  s[EPT], d[EPT], slot[EPT];
    bool v[EPT];
    #pragma unroll
    for (int k = 0; k < EPT; ++k) {
        const int e = base + 256 * k;
        v[k] = (e < N_EDGES);
        s[k] = v[k] ? ei[e] : 0;
        d[k] = v[k] ? ei[N_EDGES + e] : 0;
    }

    #pragma unroll
    for (int k = 0; k < EPT; ++k)
        slot[k] = v[k] ? atomicAdd(&degp[(long)d[k] * DEG_STRIDE], 1) : 0;

    float4 ps[EPT], pd[EPT];
    #pragma unroll
    for (int k = 0; k < EPT; ++k) { ps[k] = pos4[s[k]]; pd[k] = pos4[d[k]]; }

    #pragma unroll
    for (int k = 0; k < EPT; ++k)
        if (v[k] && slot[k] < SLOT_STRIDE)
            esrc[((long)d[k] << 6) + slot[k]] = s[k];

    float dist[EPT];
    #pragma unroll
    for (int k = 0; k < EPT; ++k) {
        const float dx = ps[k].x - pd[k].x;
        const float dy = ps[k].y - pd[k].y;
        const float dz = ps[k].z - pd[k].z;
        dist[k] = sqrtf(dx * dx + dy * dy + dz * dz);
    }

    float z[EPT] = {0.f, 0.f, 0.f, 0.f};
    #pragma unroll 4
    for (int b = 0; b < NB; ++b) {
        const float4 t4 = pkt[b];
        #pragma unroll
        for (int k = 0; k < EPT; ++k) {
            const float t = (dist[k] - t4.x) * t4.y;
            z[k] = fmaf(__expf(-0.5f * t * t), t4.z, z[k]);
        }
    }

    float sig = 0.0f;
    #pragma unroll
    for (int k = 0; k < EPT; ++k) {
        if (v[k]) {
            const float cut = (dist[k] <= CUTOFF)
                            ? 0.5f * (__cosf(PI_F * dist[k] * (1.0f / CUTOFF)) + 1.0f)
                            : 0.0f;
            sig += 1.0f / (1.0f + __expf(-(z[k] * cut + bias)));
        }
    }

    #pragma unroll
    for (int off = 32; off > 0; off >>= 1) sig += __shfl_xor(sig, off);
    __shared__ float red[4];
    if ((threadIdx.x & 63) == 0) red[threadIdx.x >> 6] = sig;
    __syncthreads();
    if (threadIdx.x == 0)
        atomicAdd(ew_accum, red[0] + red[1] + red[2] + red[3]);
}

// ---------------------------------------------------------------------------
// K2: FUSED gather + node transform. Block owns 64 nodes.
//  Phase A: weights -> registers (loads issued first, retire under gather);
//           4 waves x 16 nodes wave-per-node gather (round-6's proven shape,
//           node PAIRS for 2x MLP) directly into the sA tile.
//  Phase B: one barrier, then round-6's transform (scalar node-quad x
//           out-quad channel + vector channel), writing final out rows.
// Deletes the 64 MB agg round-trip and overlaps gather memory time with
// transform compute across the 2 resident blocks/CU.
// LDS = 41984 + 16384 + 4096 = 62464 B -> 2 blocks/CU.
// ---------------------------------------------------------------------------
#define ROWP 164
#define TNODES 64

__global__ __launch_bounds__(256) void gather_node_fused(
    const float* __restrict__ x, const int* __restrict__ degp,
    const int* __restrict__ esrc, float* __restrict__ out,
    const float* __restrict__ W0, const float* __restrict__ W1,
    const float* __restrict__ ln_gamma, const float* __restrict__ ln_beta,
    const float* __restrict__ ew_accum)
{
    __shared__ float sA[TNODES * ROWP];   // 64 x 164
    __shared__ float sW0[64 * 64];
    __shared__ float sW1[32 * 32];

    const int t    = threadIdx.x;
    const int lane = t & 63;
    const int w    = t >> 6;                 // wave 0..3
    const int node0 = blockIdx.x * TNODES;

    // ---- weight loads into registers (issued before gather; L2-hot) ----
    float4 w0r[4];
    #pragma unroll
    for (int i = 0; i < 4; ++i) w0r[i] = ((const float4*)W0)[t + 256 * i];
    const float4 w1r = ((const float4*)W1)[t];

    // ---- gather: wave w owns nodes node0+16w .. +15, processed in pairs ----
    #pragma unroll 1
    for (int p = 0; p < 16; p += 2) {
        const int nlA = w * 16 + p;
        const int nlB = nlA + 1;
        const int nA  = node0 + nlA;
        const int nB  = node0 + nlB;
        const long nAc = (nA < N_NODES) ? nA : 0;
        const long nBc = (nB < N_NODES) ? nB : 0;

        // slot lines + degs for both nodes issue concurrently
        const int svA  = esrc[(nAc << 6) + lane];
        const int svB  = esrc[(nBc << 6) + lane];
        const int cntA = (nA < N_NODES) ? min(degp[nAc * DEG_STRIDE], SLOT_STRIDE) : 0;
        const int cntB = (nB < N_NODES) ? min(degp[nBc * DEG_STRIDE], SLOT_STRIDE) : 0;

        float4 aA = make_float4(0.f, 0.f, 0.f, 0.f);
        float4 aB = make_float4(0.f, 0.f, 0.f, 0.f);

        #define GBODY(sv, cnt, acc)                                            \
        {                                                                      \
            int j = 0;                                                         \
            for (; j + 8 <= cnt; j += 8) {                                     \
                const int s0 = __shfl(sv, j);                                  \
                const int s1 = __shfl(sv, j + 1);                              \
                const int s2 = __shfl(sv, j + 2);                              \
                const int s3 = __shfl(sv, j + 3);                              \
                const int s4 = __shfl(sv, j + 4);                              \
                const int s5 = __shfl(sv, j + 5);                              \
                const int s6 = __shfl(sv, j + 6);                              \
                const int s7 = __shfl(sv, j + 7);                              \
                if (lane < 40) {                                               \
                    const float4 v0 = ((const float4*)(x + (long)s0 * DIM))[lane]; \
                    const float4 v1 = ((const float4*)(x + (long)s1 * DIM))[lane]; \
                    const float4 v2 = ((const float4*)(x + (long)s2 * DIM))[lane]; \
                    const float4 v3 = ((const float4*)(x + (long)s3 * DIM))[lane]; \
                    const float4 v4 = ((const float4*)(x + (long)s4 * DIM))[lane]; \
                    const float4 v5 = ((const float4*)(x + (long)s5 * DIM))[lane]; \
                    const float4 v6 = ((const float4*)(x + (long)s6 * DIM))[lane]; \
                    const float4 v7 = ((const float4*)(x + (long)s7 * DIM))[lane]; \
                    acc.x += ((v0.x + v1.x) + (v2.x + v3.x)) + ((v4.x + v5.x) + (v6.x + v7.x)); \
                    acc.y += ((v0.y + v1.y) + (v2.y + v3.y)) + ((v4.y + v5.y) + (v6.y + v7.y)); \
                    acc.z += ((v0.z + v1.z) + (v2.z + v3.z)) + ((v4.z + v5.z) + (v6.z + v7.z)); \
                    acc.w += ((v0.w + v1.w) + (v2.w + v3.w)) + ((v4.w + v5.w) + (v6.w + v7.w)); \
                }                                                              \
            }                                                                  \
            for (; j + 4 <= cnt; j += 4) {                                     \
                const int s0 = __shfl(sv, j);                                  \
                const int s1 = __shfl(sv, j + 1);                              \
                const int s2 = __shfl(sv, j + 2);                              \
                const int s3 = __shfl(sv, j + 3);                              \
                if (lane < 40) {                                               \
                    const float4 v0 = ((const float4*)(x + (long)s0 * DIM))[lane]; \
                    const float4 v1 = ((const float4*)(x + (long)s1 * DIM))[lane]; \
                    const float4 v2 = ((const float4*)(x + (long)s2 * DIM))[lane]; \
                    const float4 v3 = ((const float4*)(x + (long)s3 * DIM))[lane]; \
                    acc.x += (v0.x + v1.x) + (v2.x + v3.x);                    \
                    acc.y += (v0.y + v1.y) + (v2.y + v3.y);                    \
                    acc.z += (v0.z + v1.z) + (v2.z + v3.z);                    \
                    acc.w += (v0.w + v1.w) + (v2.w + v3.w);                    \
                }                                                              \
            }                                                                  \
            for (; j < cnt; ++j) {                                             \
                const int s0 = __shfl(sv, j);                                  \
                if (lane < 40) {                                               \
                    const float4 v0 = ((const float4*)(x + (long)s0 * DIM))[lane]; \
                    acc.x += v0.x; acc.y += v0.y; acc.z += v0.z; acc.w += v0.w; \
                }                                                              \
            }                                                                  \
        }
        GBODY(svA, cntA, aA)
        GBODY(svB, cntB, aB)
        #undef GBODY

        if (lane < 40) {
            *(float4*)(&sA[nlA * ROWP + 4 * lane]) = aA;
            *(float4*)(&sA[nlB * ROWP + 4 * lane]) = aB;
        }
    }

    // ---- park weights in LDS (loads long retired) ----
    {
        float4* s04 = (float4*)sW0;
        #pragma unroll
        for (int i = 0; i < 4; ++i) s04[t + 256 * i] = w0r[i];
        ((float4*)sW1)[t] = w1r;
    }
    __syncthreads();

    const float ew   = ew_accum[0] * (1.0f / 400000.0f);
    const float s_m0 = ew * 0.125f;                 // / sqrt(64)
    const float s_m1 = ew * 0.17677669529663687f;   // / sqrt(32)

    // ---------------- scalar channel (node-quad x output-quad) ----------------
    {
        const int q   = t >> 4;          // 0..15 node quad
        const int sub = t & 15;          // 0..15 output quad
        const float* r0 = sA + (4 * q + 0) * ROWP;
        const float* r1 = sA + (4 * q + 1) * ROWP;
        const float* r2 = sA + (4 * q + 2) * ROWP;
        const float* r3 = sA + (4 * q + 3) * ROWP;

        float acc[4][4];
        #pragma unroll
        for (int n = 0; n < 4; ++n)
            #pragma unroll
            for (int j = 0; j < 4; ++j) acc[n][j] = 0.0f;

        #pragma unroll 4
        for (int k0 = 0; k0 < 64; k0 += 4) {
            const float4 a0 = *(const float4*)(r0 + k0);
            const float4 a1 = *(const float4*)(r1 + k0);
            const float4 a2 = *(const float4*)(r2 + k0);
            const float4 a3 = *(const float4*)(r3 + k0);
            const float4 w0 = *(const float4*)(sW0 + (k0 + 0) * 64 + 4 * sub);
            const float4 w1 = *(const float4*)(sW0 + (k0 + 1) * 64 + 4 * sub);
            const float4 w2 = *(const float4*)(sW0 + (k0 + 2) * 64 + 4 * sub);
            const float4 w3 = *(const float4*)(sW0 + (k0 + 3) * 64 + 4 * sub);
            #define FMA4(A, av, wv) \
                A[0] = fmaf(av, wv.x, A[0]); A[1] = fmaf(av, wv.y, A[1]); \
                A[2] = fmaf(av, wv.z, A[2]); A[3] = fmaf(av, wv.w, A[3]);
            FMA4(acc[0], a0.x, w0) FMA4(acc[0], a0.y, w1) FMA4(acc[0], a0.z, w2) FMA4(acc[0], a0.w, w3)
            FMA4(acc[1], a1.x, w0) FMA4(acc[1], a1.y, w1) FMA4(acc[1], a1.z, w2) FMA4(acc[1], a1.w, w3)
            FMA4(acc[2], a2.x, w0) FMA4(acc[2], a2.y, w1) FMA4(acc[2], a2.z, w2) FMA4(acc[2], a2.w, w3)
            FMA4(acc[3], a3.x, w0) FMA4(acc[3], a3.y, w1) FMA4(acc[3], a3.z, w2) FMA4(acc[3], a3.w, w3)
            #undef FMA4
        }

        float sum[4], ssq[4];
        #pragma unroll
        for (int n = 0; n < 4; ++n) {
            sum[n] = 0.0f; ssq[n] = 0.0f;
            #pragma unroll
            for (int j = 0; j < 4; ++j) {
                acc[n][j] *= s_m0;
                sum[n] += acc[n][j];
                ssq[n] = fmaf(acc[n][j], acc[n][j], ssq[n]);
            }
        }
        #pragma unroll
        for (int m = 1; m <= 8; m <<= 1) {
            #pragma unroll
            for (int n = 0; n < 4; ++n) {
                sum[n] += __shfl_xor(sum[n], m);
                ssq[n] += __shfl_xor(ssq[n], m);
            }
        }

        const float4 g = *(const float4*)(ln_gamma + 4 * sub);
        const float4 b = *(const float4*)(ln_beta  + 4 * sub);
        #pragma unroll
        for (int n = 0; n < 4; ++n) {
            const int node = node0 + 4 * q + n;
            if (node < N_NODES) {
                const float mu   = sum[n] * (1.0f / 64.0f);
                const float var  = ssq[n] * (1.0f / 64.0f) - mu * mu;
                const float rstd = rsqrtf(var + LN_EPS);
                const float t0 = (acc[n][0] - mu) * rstd * g.x + b.x;
                const float t1 = (acc[n][1] - mu) * rstd * g.y + b.y;
                const float t2 = (acc[n][2] - mu) * rstd * g.z + b.z;
                const float t3 = (acc[n][3] - mu) * rstd * g.w + b.w;
                float4 o;
                o.x = t0 / (1.0f + __expf(-t0));
                o.y = t1 / (1.0f + __expf(-t1));
                o.z = t2 / (1.0f + __expf(-t2));
                o.w = t3 / (1.0f + __expf(-t3));
                *(float4*)(out + (long)node * DIM + 4 * sub) = o;
            }
        }
    }

    // ---------------- vector channel ----------------
    {
        const int nl   = t >> 2;          // 0..63 node within tile
        const int sub  = t & 3;           // c8
        const int node = node0 + nl;
        const bool valid = node < N_NODES;
        float* grow = out + (long)(valid ? node : 0) * DIM;
        const float* aRow = sA + nl * ROWP;

        float o[24];
        #pragma unroll
        for (int m = 0; m < 24; ++m) o[m] = 0.0f;

        const float* bRow = aRow + 64;
        #pragma unroll 2
        for (int tt = 0; tt < 8; ++tt) {            // cp = 4tt + r
            const float4 v0 = *(const float4*)(bRow + 12 * tt);
            const float4 v1 = *(const float4*)(bRow + 12 * tt + 4);
            const float4 v2 = *(const float4*)(bRow + 12 * tt + 8);
            const float a[12] = { v0.x, v0.y, v0.z, v0.w,
                                  v1.x, v1.y, v1.z, v1.w,
                                  v2.x, v2.y, v2.z, v2.w };
            #pragma unroll
            for (int r = 0; r < 4; ++r) {
                const int cp = 4 * tt + r;
                const float a0 = a[3 * r];
                const float a1 = a[3 * r + 1];
                const float a2 = a[3 * r + 2];
                const float4* w4 = (const float4*)(sW1 + cp * 32 + sub * 8);
                const float4 wA = w4[0];
                const float4 wB = w4[1];
                const float wc[8] = { wA.x, wA.y, wA.z, wA.w, wB.x, wB.y, wB.z, wB.w };
                #pragma unroll
                for (int cc = 0; cc < 8; ++cc) {
                    o[3 * cc]     = fmaf(wc[cc], a0, o[3 * cc]);
                    o[3 * cc + 1] = fmaf(wc[cc], a1, o[3 * cc + 1]);
                    o[3 * cc + 2] = fmaf(wc[cc], a2, o[3 * cc + 2]);
                }
            }
        }

        if (valid) {
            float4* ro4 = (float4*)(grow + 64 + 24 * sub);
            #pragma unroll
            for (int q2 = 0; q2 < 6; ++q2) {
                float4 ov;
                ov.x = o[4 * q2]     * s_m1;
                ov.y = o[4 * q2 + 1] * s_m1;
                ov.z = o[4 * q2 + 2] * s_m1;
                ov.w = o[4 * q2 + 3] * s_m1;
                ro4[q2] = ov;
            }
        }
    }
}

extern "C" void kernel_launch(void* const* d_in, const int* in_sizes, int n_in,
                              void* d_out, int out_size, void* d_ws, size_t ws_size,
                              hipStream_t stream) {
    const float* x       = (const float*)d_in[0];
    const float* pos     = (const float*)d_in[1];
    const int*   ei      = (const int*)d_in[2];
    const float* W0      = (const float*)d_in[4];
    const float* W1      = (const float*)d_in[5];
    const float* centers = (const float*)d_in[6];
    const float* widths  = (const float*)d_in[7];
    const float* proj_w  = (const float*)d_in[8];
    const float* proj_b  = (const float*)d_in[9];
    const float* gamma   = (const float*)d_in[10];
    const float* beta    = (const float*)d_in[11];

    float* out  = (float*)d_out;
    int*   wsi  = (int*)d_ws;
    float* ew   = (float*)d_ws;
    int*   degp = wsi + WS_DEG;
    float4* pkt  = (float4*)(wsi + WS_PKT);
    float4* pos4 = (float4*)(wsi + WS_POS4);
    int*   esrc = wsi + WS_ESRC;

    const int pb = (N_NODES + 255) / 256;
    prep<<<pb, 256, 0, stream>>>(pos, centers, widths, proj_w, degp, pkt, pos4, ew);

    const int eb = (N_EDGES + 256 * EPT - 1) / (256 * EPT);   // 391
    hist_ew_fill<<<eb, 256, 0, stream>>>(ei, pos4, pkt, proj_b, degp, esrc, ew);

    const int tiles = (N_NODES + TNODES - 1) / TNODES;   // 782
    gather_node_fused<<<tiles, 256, 0, stream>>>(x, degp, esrc, out,
                                                 W0, W1, gamma, beta, ew);
}

// Round 9
// 190.935 us; speedup vs baseline: 1.0531x; 1.0524x over previous
//
#include <hip/hip_runtime.h>

#define N_NODES 50000
#define N_EDGES 400000
#define DIM 160
#define NB 64
#define CUTOFF 5.0f
#define LN_EPS 1e-5f
#define PI_F 3.14159265358979323846f

// Padded CSR: stride-64 slot list per destination node.
#define SLOT_STRIDE 64
// deg padded to one counter per 16B.
#define DEG_STRIDE 4

// Workspace (ints), total 3,600,272 ints = 13.73 MiB:
#define WS_DEG   16
#define WS_PKT   (WS_DEG + N_NODES * DEG_STRIDE)   // 200016
#define WS_POS4  (WS_PKT + 4 * NB)                 // 200272
#define WS_ESRC  (WS_POS4 + 4 * N_NODES)           // 400272

// ---------------------------------------------------------------------------
// K0: prep (unchanged).
// ---------------------------------------------------------------------------
__global__ __launch_bounds__(256) void prep(
    const float* __restrict__ pos, const float* __restrict__ centers,
    const float* __restrict__ widths, const float* __restrict__ proj_w,
    int* __restrict__ degp, float4* __restrict__ pkt,
    float4* __restrict__ pos4, float* __restrict__ ew_accum)
{
    const int i = blockIdx.x * blockDim.x + threadIdx.x;
    if (i < 16) ((int*)ew_accum)[i] = 0;
    if (i < NB)
        pkt[i] = make_float4(centers[i], 1.0f / widths[i], proj_w[i], 0.0f);
    if (i < N_NODES) {
        ((int4*)(degp))[i] = make_int4(0, 0, 0, 0);
        pos4[i] = make_float4(pos[3 * i], pos[3 * i + 1], pos[3 * i + 2], 0.0f);
    }
}

// ---------------------------------------------------------------------------
// K1: hist_ew_fill (unchanged from rounds 5/6: EPT=4, padded counters).
// ---------------------------------------------------------------------------
#define EPT 4

__global__ __launch_bounds__(256) void hist_ew_fill(
    const int* __restrict__ ei, const float4* __restrict__ pos4,
    const float4* __restrict__ pkt, const float* __restrict__ proj_b,
    int* __restrict__ degp, int* __restrict__ esrc, float* __restrict__ ew_accum)
{
    const float bias = proj_b[0];
    const int base = blockIdx.x * (256 * EPT) + threadIdx.x;

    int  s[EPT], d[EPT], slot[EPT];
    bool v[EPT];
    #pragma unroll
    for (int k = 0; k < EPT; ++k) {
        const int e = base + 256 * k;
        v[k] = (e < N_EDGES);
        s[k] = v[k] ? ei[e] : 0;
        d[k] = v[k] ? ei[N_EDGES + e] : 0;
    }

    #pragma unroll
    for (int k = 0; k < EPT; ++k)
        slot[k] = v[k] ? atomicAdd(&degp[(long)d[k] * DEG_STRIDE], 1) : 0;

    float4 ps[EPT], pd[EPT];
    #pragma unroll
    for (int k = 0; k < EPT; ++k) { ps[k] = pos4[s[k]]; pd[k] = pos4[d[k]]; }

    #pragma unroll
    for (int k = 0; k < EPT; ++k)
        if (v[k] && slot[k] < SLOT_STRIDE)
            esrc[((long)d[k] << 6) + slot[k]] = s[k];

    float dist[EPT];
    #pragma unroll
    for (int k = 0; k < EPT; ++k) {
        const float dx = ps[k].x - pd[k].x;
        const float dy = ps[k].y - pd[k].y;
        const float dz = ps[k].z - pd[k].z;
        dist[k] = sqrtf(dx * dx + dy * dy + dz * dz);
    }

    float z[EPT] = {0.f, 0.f, 0.f, 0.f};
    #pragma unroll 4
    for (int b = 0; b < NB; ++b) {
        const float4 t4 = pkt[b];
        #pragma unroll
        for (int k = 0; k < EPT; ++k) {
            const float t = (dist[k] - t4.x) * t4.y;
            z[k] = fmaf(__expf(-0.5f * t * t), t4.z, z[k]);
        }
    }

    float sig = 0.0f;
    #pragma unroll
    for (int k = 0; k < EPT; ++k) {
        if (v[k]) {
            const float cut = (dist[k] <= CUTOFF)
                            ? 0.5f * (__cosf(PI_F * dist[k] * (1.0f / CUTOFF)) + 1.0f)
                            : 0.0f;
            sig += 1.0f / (1.0f + __expf(-(z[k] * cut + bias)));
        }
    }

    #pragma unroll
    for (int off = 32; off > 0; off >>= 1) sig += __shfl_xor(sig, off);
    __shared__ float red[4];
    if ((threadIdx.x & 63) == 0) red[threadIdx.x >> 6] = sig;
    __syncthreads();
    if (threadIdx.x == 0)
        atomicAdd(ew_accum, red[0] + red[1] + red[2] + red[3]);
}

// ---------------------------------------------------------------------------
// K2: wave-per-node gather (round-6 version, measured 41.6-41.8 us; best).
// ---------------------------------------------------------------------------
__global__ __launch_bounds__(256) void gather_pass(
    const float* __restrict__ x, const int* __restrict__ degp,
    const int* __restrict__ esrc, float* __restrict__ agg)
{
    const int lane = threadIdx.x & 63;
    const int n    = (blockIdx.x * blockDim.x + threadIdx.x) >> 6;
    if (n >= N_NODES) return;

    const int sv  = esrc[((long)n << 6) + lane];          // independent of deg
    const int cnt = min(degp[(long)n * DEG_STRIDE], SLOT_STRIDE);

    float4 acc = make_float4(0.f, 0.f, 0.f, 0.f);
    int j = 0;
    for (; j + 8 <= cnt; j += 8) {
        const int s0 = __shfl(sv, j);
        const int s1 = __shfl(sv, j + 1);
        const int s2 = __shfl(sv, j + 2);
        const int s3 = __shfl(sv, j + 3);
        const int s4 = __shfl(sv, j + 4);
        const int s5 = __shfl(sv, j + 5);
        const int s6 = __shfl(sv, j + 6);
        const int s7 = __shfl(sv, j + 7);
        if (lane < 40) {
            const float4 v0 = ((const float4*)(x + (long)s0 * DIM))[lane];
            const float4 v1 = ((const float4*)(x + (long)s1 * DIM))[lane];
            const float4 v2 = ((const float4*)(x + (long)s2 * DIM))[lane];
            const float4 v3 = ((const float4*)(x + (long)s3 * DIM))[lane];
            const float4 v4 = ((const float4*)(x + (long)s4 * DIM))[lane];
            const float4 v5 = ((const float4*)(x + (long)s5 * DIM))[lane];
            const float4 v6 = ((const float4*)(x + (long)s6 * DIM))[lane];
            const float4 v7 = ((const float4*)(x + (long)s7 * DIM))[lane];
            acc.x += ((v0.x + v1.x) + (v2.x + v3.x)) + ((v4.x + v5.x) + (v6.x + v7.x));
            acc.y += ((v0.y + v1.y) + (v2.y + v3.y)) + ((v4.y + v5.y) + (v6.y + v7.y));
            acc.z += ((v0.z + v1.z) + (v2.z + v3.z)) + ((v4.z + v5.z) + (v6.z + v7.z));
            acc.w += ((v0.w + v1.w) + (v2.w + v3.w)) + ((v4.w + v5.w) + (v6.w + v7.w));
        }
    }
    for (; j + 4 <= cnt; j += 4) {
        const int s0 = __shfl(sv, j);
        const int s1 = __shfl(sv, j + 1);
        const int s2 = __shfl(sv, j + 2);
        const int s3 = __shfl(sv, j + 3);
        if (lane < 40) {
            const float4 v0 = ((const float4*)(x + (long)s0 * DIM))[lane];
            const float4 v1 = ((const float4*)(x + (long)s1 * DIM))[lane];
            const float4 v2 = ((const float4*)(x + (long)s2 * DIM))[lane];
            const float4 v3 = ((const float4*)(x + (long)s3 * DIM))[lane];
            acc.x += (v0.x + v1.x) + (v2.x + v3.x);
            acc.y += (v0.y + v1.y) + (v2.y + v3.y);
            acc.z += (v0.z + v1.z) + (v2.z + v3.z);
            acc.w += (v0.w + v1.w) + (v2.w + v3.w);
        }
    }
    for (; j < cnt; ++j) {
        const int s0 = __shfl(sv, j);
        if (lane < 40) {
            const float4 v0 = ((const float4*)(x + (long)s0 * DIM))[lane];
            acc.x += v0.x; acc.y += v0.y; acc.z += v0.z; acc.w += v0.w;
        }
    }
    if (lane < 40)
        ((float4*)(agg + (long)n * DIM))[lane] = acc;
}

// ---------------------------------------------------------------------------
// K3: node transform, NO row tile. Only W0+W1 in LDS (20 KB -> high occup).
// A-operands read DIRECTLY from global:
//   scalar: a-reads are quad-uniform (16 threads same 16B -> HW broadcast);
//   vector: row reads are 4-lane-uniform. Each row element read once/block.
// Deletes the 42 KB sA tile, its staging pass, its drain barrier, and ~60%
// of the LDS-pipe traffic that bounded round-6's node_tiled.
// In-place safe: each wave owns rows 16w..16w+15 for BOTH channels; reads of
// a column range complete (wave-lockstep) before its writes; scalar writes
// cols 0..63, vector reads cols 64..159 (disjoint).
// ---------------------------------------------------------------------------
#define TNODES 64

__global__ __launch_bounds__(256) void node_direct(
    float* __restrict__ agg,
    const float* __restrict__ W0, const float* __restrict__ W1,
    const float* __restrict__ ln_gamma, const float* __restrict__ ln_beta,
    const float* __restrict__ ew_accum)
{
    __shared__ float sW0[64 * 64];
    __shared__ float sW1[32 * 32];

    const int t = threadIdx.x;
    const int node0 = blockIdx.x * TNODES;

    {
        const float4* w04 = (const float4*)W0;   // 1024 float4
        float4* s04 = (float4*)sW0;
        #pragma unroll
        for (int i = 0; i < 4; ++i) s04[t + 256 * i] = w04[t + 256 * i];
        ((float4*)sW1)[t] = ((const float4*)W1)[t];
    }
    __syncthreads();

    const float ew   = ew_accum[0] * (1.0f / 400000.0f);
    const float s_m0 = ew * 0.125f;                 // / sqrt(64)
    const float s_m1 = ew * 0.17677669529663687f;   // / sqrt(32)

    // ---------------- scalar channel (node-quad x output-quad) ----------------
    {
        const int q   = t >> 4;          // 0..15 node quad: nodes 4q..4q+3
        const int sub = t & 15;          // 0..15 output quad
        const int n0  = node0 + 4 * q;
        const float* r0 = agg + (long)((n0 + 0 < N_NODES) ? n0 + 0 : 0) * DIM;
        const float* r1 = agg + (long)((n0 + 1 < N_NODES) ? n0 + 1 : 0) * DIM;
        const float* r2 = agg + (long)((n0 + 2 < N_NODES) ? n0 + 2 : 0) * DIM;
        const float* r3 = agg + (long)((n0 + 3 < N_NODES) ? n0 + 3 : 0) * DIM;

        float acc[4][4];
        #pragma unroll
        for (int n = 0; n < 4; ++n)
            #pragma unroll
            for (int j = 0; j < 4; ++j) acc[n][j] = 0.0f;

        #pragma unroll 4
        for (int k0 = 0; k0 < 64; k0 += 4) {
            const float4 a0 = *(const float4*)(r0 + k0);   // quad-uniform bcast
            const float4 a1 = *(const float4*)(r1 + k0);
            const float4 a2 = *(const float4*)(r2 + k0);
            const float4 a3 = *(const float4*)(r3 + k0);
            const float4 w0 = *(const float4*)(sW0 + (k0 + 0) * 64 + 4 * sub);
            const float4 w1 = *(const float4*)(sW0 + (k0 + 1) * 64 + 4 * sub);
            const float4 w2 = *(const float4*)(sW0 + (k0 + 2) * 64 + 4 * sub);
            const float4 w3 = *(const float4*)(sW0 + (k0 + 3) * 64 + 4 * sub);
            #define FMA4(A, av, wv) \
                A[0] = fmaf(av, wv.x, A[0]); A[1] = fmaf(av, wv.y, A[1]); \
                A[2] = fmaf(av, wv.z, A[2]); A[3] = fmaf(av, wv.w, A[3]);
            FMA4(acc[0], a0.x, w0) FMA4(acc[0], a0.y, w1) FMA4(acc[0], a0.z, w2) FMA4(acc[0], a0.w, w3)
            FMA4(acc[1], a1.x, w0) FMA4(acc[1], a1.y, w1) FMA4(acc[1], a1.z, w2) FMA4(acc[1], a1.w, w3)
            FMA4(acc[2], a2.x, w0) FMA4(acc[2], a2.y, w1) FMA4(acc[2], a2.z, w2) FMA4(acc[2], a2.w, w3)
            FMA4(acc[3], a3.x, w0) FMA4(acc[3], a3.y, w1) FMA4(acc[3], a3.z, w2) FMA4(acc[3], a3.w, w3)
            #undef FMA4
        }

        float sum[4], ssq[4];
        #pragma unroll
        for (int n = 0; n < 4; ++n) {
            sum[n] = 0.0f; ssq[n] = 0.0f;
            #pragma unroll
            for (int j = 0; j < 4; ++j) {
                acc[n][j] *= s_m0;
                sum[n] += acc[n][j];
                ssq[n] = fmaf(acc[n][j], acc[n][j], ssq[n]);
            }
        }
        #pragma unroll
        for (int m = 1; m <= 8; m <<= 1) {
            #pragma unroll
            for (int n = 0; n < 4; ++n) {
                sum[n] += __shfl_xor(sum[n], m);
                ssq[n] += __shfl_xor(ssq[n], m);
            }
        }

        const float4 g = *(const float4*)(ln_gamma + 4 * sub);
        const float4 b = *(const float4*)(ln_beta  + 4 * sub);
        #pragma unroll
        for (int n = 0; n < 4; ++n) {
            const int node = node0 + 4 * q + n;
            if (node < N_NODES) {
                const float mu   = sum[n] * (1.0f / 64.0f);
                const float var  = ssq[n] * (1.0f / 64.0f) - mu * mu;
                const float rstd = rsqrtf(var + LN_EPS);
                const float t0 = (acc[n][0] - mu) * rstd * g.x + b.x;
                const float t1 = (acc[n][1] - mu) * rstd * g.y + b.y;
                const float t2 = (acc[n][2] - mu) * rstd * g.z + b.z;
                const float t3 = (acc[n][3] - mu) * rstd * g.w + b.w;
                float4 o;
                o.x = t0 / (1.0f + __expf(-t0));
                o.y = t1 / (1.0f + __expf(-t1));
                o.z = t2 / (1.0f + __expf(-t2));
                o.w = t3 / (1.0f + __expf(-t3));
                *(float4*)(agg + (long)node * DIM + 4 * sub) = o;
            }
        }
    }

    // ---------------- vector channel (rows from global, 4-lane bcast) --------
    {
        const int nl   = t >> 2;          // 0..63 node within tile
        const int sub  = t & 3;           // c8
        const int node = node0 + nl;
        const bool valid = node < N_NODES;
        float* grow = agg + (long)(valid ? node : 0) * DIM;
        const float* bRow = grow + 64;

        float o[24];
        #pragma unroll
        for (int m = 0; m < 24; ++m) o[m] = 0.0f;

        #pragma unroll 2
        for (int tt = 0; tt < 8; ++tt) {            // cp = 4tt + r
            const float4 v0 = *(const float4*)(bRow + 12 * tt);
            const float4 v1 = *(const float4*)(bRow + 12 * tt + 4);
            const float4 v2 = *(const float4*)(bRow + 12 * tt + 8);
            const float a[12] = { v0.x, v0.y, v0.z, v0.w,
                                  v1.x, v1.y, v1.z, v1.w,
                                  v2.x, v2.y, v2.z, v2.w };
            #pragma unroll
            for (int r = 0; r < 4; ++r) {
                const int cp = 4 * tt + r;
                const float a0 = a[3 * r];
                const float a1 = a[3 * r + 1];
                const float a2 = a[3 * r + 2];
                const float4* w4 = (const float4*)(sW1 + cp * 32 + sub * 8);
                const float4 wA = w4[0];
                const float4 wB = w4[1];
                const float wc[8] = { wA.x, wA.y, wA.z, wA.w, wB.x, wB.y, wB.z, wB.w };
                #pragma unroll
                for (int cc = 0; cc < 8; ++cc) {
                    o[3 * cc]     = fmaf(wc[cc], a0, o[3 * cc]);
                    o[3 * cc + 1] = fmaf(wc[cc], a1, o[3 * cc + 1]);
                    o[3 * cc + 2] = fmaf(wc[cc], a2, o[3 * cc + 2]);
                }
            }
        }

        if (valid) {
            float4* ro4 = (float4*)(grow + 64 + 24 * sub);
            #pragma unroll
            for (int q2 = 0; q2 < 6; ++q2) {
                float4 ov;
                ov.x = o[4 * q2]     * s_m1;
                ov.y = o[4 * q2 + 1] * s_m1;
                ov.z = o[4 * q2 + 2] * s_m1;
                ov.w = o[4 * q2 + 3] * s_m1;
                ro4[q2] = ov;
            }
        }
    }
}

extern "C" void kernel_launch(void* const* d_in, const int* in_sizes, int n_in,
                              void* d_out, int out_size, void* d_ws, size_t ws_size,
                              hipStream_t stream) {
    const float* x       = (const float*)d_in[0];
    const float* pos     = (const float*)d_in[1];
    const int*   ei      = (const int*)d_in[2];
    const float* W0      = (const float*)d_in[4];
    const float* W1      = (const float*)d_in[5];
    const float* centers = (const float*)d_in[6];
    const float* widths  = (const float*)d_in[7];
    const float* proj_w  = (const float*)d_in[8];
    const float* proj_b  = (const float*)d_in[9];
    const float* gamma   = (const float*)d_in[10];
    const float* beta    = (const float*)d_in[11];

    float* out  = (float*)d_out;
    int*   wsi  = (int*)d_ws;
    float* ew   = (float*)d_ws;
    int*   degp = wsi + WS_DEG;
    float4* pkt  = (float4*)(wsi + WS_PKT);
    float4* pos4 = (float4*)(wsi + WS_POS4);
    int*   esrc = wsi + WS_ESRC;

    const int pb = (N_NODES + 255) / 256;
    prep<<<pb, 256, 0, stream>>>(pos, centers, widths, proj_w, degp, pkt, pos4, ew);

    const int eb = (N_EDGES + 256 * EPT - 1) / (256 * EPT);   // 391
    hist_ew_fill<<<eb, 256, 0, stream>>>(ei, pos4, pkt, proj_b, degp, esrc, ew);

    const int nb = (N_NODES * 64 + 255) / 256;
    gather_pass<<<nb, 256, 0, stream>>>(x, degp, esrc, out);

    const int tiles = (N_NODES + TNODES - 1) / TNODES;   // 782
    node_direct<<<tiles, 256, 0, stream>>>(out, W0, W1, gamma, beta, ew);
}